// Round 5
// baseline (642.993 us; speedup 1.0000x reference)
//
#include <hip/hip_runtime.h>

#define NB 2048
#define NT 2048
#define NH 16

#define OFF_IMP   1L
#define OFF_TRAIN (1L + (long)NB * NT)
#define OFF_EVALS (OFF_TRAIN + NB)
#define OFF_EMASK (OFF_EVALS + (long)NB * NT)

// ws layout: num_t[NT] | den_t[NT] | amt[NB*NT] (path A)  or  rep[NREP*NT] (path B)
#define WS_AMT_OFF 4096
#define NREP 64

typedef float f2 __attribute__((ext_vector_type(2)));

// ---------------- copies + workspace zeroing ----------------
__global__ void copy_zero_kernel(const float* __restrict__ evals,
                                 const float* __restrict__ emask,
                                 const float* __restrict__ is_train,
                                 float* __restrict__ out,
                                 float* __restrict__ ws,
                                 int n_zero) {
    long gid = (long)blockIdx.x * blockDim.x + threadIdx.x;
    if (gid < n_zero) ws[gid] = 0.0f;
    const long n1 = (long)NB * NT;
    const long total = NB + 2 * n1;
    const long stride = (long)gridDim.x * blockDim.x;
    for (long i = gid; i < total; i += stride) {
        if (i < NB)            out[OFF_TRAIN + i] = is_train[i];
        else if (i < NB + n1)  out[OFF_EVALS + (i - NB)] = evals[i - NB];
        else                   out[OFF_EMASK + (i - NB - n1)] = emask[i - NB - n1];
    }
}

// ---------------- LSTM scan: gate-parallel, 64 lanes = 1 batch ----------------
// lane = gate*16 + j  (gate order: i, f, g, o — torch LSTMCell)
__device__ __forceinline__ float rl(float v, int srcLane) {
    return __int_as_float(__builtin_amdgcn_readlane(__float_as_int(v), srcLane));
}

// One LSTM step. ARITHMETIC FROZEN (absmax-sensitive recurrence): identical
// op order to the round-4 kernel; only the h-broadcast mechanism differs
// (v_readlane instead of LDS write+read — bit-exact copy, off the LDS pipe).
#define STEP(xx, mm, XI, AI) do {                                              \
    f2 dA = H2[0] * Wh2[0];                                                    \
    f2 dB = H2[1] * Wh2[1];                                                    \
    dA = __builtin_elementwise_fma(H2[2], Wh2[2], dA);                         \
    dB = __builtin_elementwise_fma(H2[3], Wh2[3], dB);                         \
    dA = __builtin_elementwise_fma(H2[4], Wh2[4], dA);                         \
    dB = __builtin_elementwise_fma(H2[5], Wh2[5], dB);                         \
    dA = __builtin_elementwise_fma(H2[6], Wh2[6], dA);                         \
    dB = __builtin_elementwise_fma(H2[7], Wh2[7], dB);                         \
    f2 rA = H2[0] * Wr2[0];                                                    \
    f2 rB = H2[1] * Wr2[1];                                                    \
    rA = __builtin_elementwise_fma(H2[2], Wr2[2], rA);                         \
    rB = __builtin_elementwise_fma(H2[3], Wr2[3], rB);                         \
    rA = __builtin_elementwise_fma(H2[4], Wr2[4], rA);                         \
    rB = __builtin_elementwise_fma(H2[5], Wr2[5], rB);                         \
    rA = __builtin_elementwise_fma(H2[6], Wr2[6], rA);                         \
    rB = __builtin_elementwise_fma(H2[7], Wr2[7], rB);                         \
    const float dot = (dA.x + dA.y) + (dB.x + dB.y);                           \
    const float xh  = brg + ((rA.x + rA.y) + (rB.x + rB.y));                   \
    const float dxm = (xx) - xh;                                               \
    const float xc  = fmaf((mm), dxm, xh);                                     \
    const float av  = fabsf(dxm) * (mm);                                       \
    const float gate = fmaf(wx0, xc, dot + fmaf(wx1, (mm), bias));             \
    const float ex  = __builtin_amdgcn_exp2f(gate * cExp);                     \
    const float act = fmaf(sMul, __builtin_amdgcn_rcpf(1.0f + ex), sAdd);      \
    const int   ia  = __float_as_int(act);                                     \
    const float af  = __int_as_float(__builtin_amdgcn_ds_swizzle(ia, 0x401F)); \
    const float ag  = __int_as_float(__builtin_amdgcn_ds_bpermute(a32, ia));   \
    const float ao  = __int_as_float(__builtin_amdgcn_ds_bpermute(a48, ia));   \
    c = fmaf(af, c, act * ag);                                                 \
    const float e2 = __builtin_amdgcn_exp2f(c * cT);                           \
    const float th = fmaf(2.0f, __builtin_amdgcn_rcpf(1.0f + e2), -1.0f);      \
    const float ht = ao * th;                                                  \
    _Pragma("unroll")                                                          \
    for (int p = 0; p < 8; ++p) {                                              \
        H2[p].x = rl(ht, 2 * p);                                               \
        H2[p].y = rl(ht, 2 * p + 1);                                           \
    }                                                                          \
    XI = xc; AI = av;                                                          \
} while (0)

#define QUAD(XV, MV, T4) do {                                                  \
    float xi0, xi1, xi2, xi3, ai0, ai1, ai2, ai3;                              \
    STEP(XV.x, MV.x, xi0, ai0); STEP(XV.y, MV.y, xi1, ai1);                    \
    STEP(XV.z, MV.z, xi2, ai2); STEP(XV.w, MV.w, xi3, ai3);                    \
    const float sx = (q == 1) ? xi1 : (q == 2) ? xi2 : (q == 3) ? xi3 : xi0;   \
    const float sa = (q == 1) ? ai1 : (q == 2) ? ai2 : (q == 3) ? ai3 : ai0;   \
    if (ATOMIC) {                                                              \
        if (lane == 0) {                                                       \
            atomicAdd(ab + (T4) + 0, ai0); atomicAdd(ab + (T4) + 1, ai1);      \
            atomicAdd(ab + (T4) + 2, ai2); atomicAdd(ab + (T4) + 3, ai3);      \
        }                                                                      \
        if (lane < 4) ib[(T4) + q] = sx;                                       \
    } else {                                                                   \
        if (lane < 8) pst[T4] = (lane < 4) ? sx : sa;                          \
    }                                                                          \
} while (0)

template <int ATOMIC>
__global__ __launch_bounds__(64, 2)
void lstm_kernel(const float* __restrict__ values,
                 const float* __restrict__ masks,
                 const float* __restrict__ W_ih,
                 const float* __restrict__ W_hh,
                 const float* __restrict__ b_ih,
                 const float* __restrict__ b_hh,
                 const float* __restrict__ W_reg,
                 const float* __restrict__ b_reg,
                 float* __restrict__ imp,   // out + OFF_IMP
                 float* __restrict__ amt) { // A: amt[NB*NT]; B: rep[NREP*NT]
    const int lane = threadIdx.x;          // 0..63
    const int G = lane >> 4;               // gate index
    const int q = lane & 3;
    const long b = blockIdx.x;             // one batch per block/wave

    f2 Wh2[8], Wr2[8];
#pragma unroll
    for (int k = 0; k < 8; ++k) {
        Wh2[k] = *(const f2*)(W_hh + lane * NH + 2 * k);
        Wr2[k] = *(const f2*)(W_reg + 2 * k);
    }
    const float wx0 = W_ih[lane * 2 + 0];
    const float wx1 = W_ih[lane * 2 + 1];
    const float bias = b_ih[lane] + b_hh[lane];
    const float brg = b_reg[0];

    const float L2E = 1.4426950408889634f;
    const float cExp = (G == 2) ? -2.0f * L2E : -L2E;  // tanh for gate g, sigmoid else
    const float cT   = -2.0f * L2E;
    const float sMul = (G == 2) ? 2.0f : 1.0f;
    const float sAdd = (G == 2) ? -1.0f : 0.0f;

    // hoisted cross-lane gather addresses (xor32 / xor48)
    const int a32 = (lane ^ 32) << 2;
    const int a48 = (lane ^ 48) << 2;

    f2 H2[8];
#pragma unroll
    for (int k = 0; k < 8; ++k) H2[k] = (f2){0.0f, 0.0f};
    float c = 0.0f;

    const float* vb = values + b * NT;
    const float* mb = masks + b * NT;
    float* ib = imp + b * NT;
    float* ab = ATOMIC ? (amt + (long)(b & (NREP - 1)) * NT) : (amt + b * NT);
    // lanes 0-3 -> imputation column q, lanes 4-7 -> loss column q
    float* pst = ((lane < 4) ? ib : ab) + q;

    // 4 static prefetch buffers, 16-step unrolled body -> no rotation movs
    float4 xA = *(const float4*)(vb + 0),  mA = *(const float4*)(mb + 0);
    float4 xB = *(const float4*)(vb + 4),  mB = *(const float4*)(mb + 4);
    float4 xC = *(const float4*)(vb + 8),  mC = *(const float4*)(mb + 8);
    float4 xD = *(const float4*)(vb + 12), mD = *(const float4*)(mb + 12);

    for (int t = 0; t < NT; t += 16) {
        QUAD(xA, mA, t + 0);
        QUAD(xB, mB, t + 4);
        {
            const int tn = (t + 16) & (NT - 1);  // wraps harmlessly on last iter
            xA = *(const float4*)(vb + tn);      mA = *(const float4*)(mb + tn);
            xB = *(const float4*)(vb + tn + 4);  mB = *(const float4*)(mb + tn + 4);
        }
        QUAD(xC, mC, t + 8);
        QUAD(xD, mD, t + 12);
        {
            const int tn = (t + 24) & (NT - 1);
            xC = *(const float4*)(vb + tn);      mC = *(const float4*)(mb + tn);
            xD = *(const float4*)(vb + tn + 4);  mD = *(const float4*)(mb + tn + 4);
        }
    }
}

// ---------------- column-sum reduce: num_t / den_t ----------------
template <int ATOMIC>
__global__ void reduce_kernel(const float* __restrict__ masks,
                              const float* __restrict__ amt,
                              float* __restrict__ num_t,
                              float* __restrict__ den_t) {
    const int t = blockIdx.x * 256 + threadIdx.x;
    const int b0 = blockIdx.y * 32;
    float sd = 0.0f;
    for (int bb = b0; bb < b0 + 32; ++bb) sd += masks[(long)bb * NT + t];
    atomicAdd(den_t + t, sd);
    if (!ATOMIC) {
        float sn = 0.0f;
        for (int bb = b0; bb < b0 + 32; ++bb) sn += amt[(long)bb * NT + t];
        atomicAdd(num_t + t, sn);
    } else if (blockIdx.y == 0) {
        float sn = 0.0f;
        for (int r = 0; r < NREP; ++r) sn += amt[(long)r * NT + t];
        num_t[t] = sn;  // single writer
    }
}

// ---------------- loss finalize ----------------
__global__ void loss_kernel(const float* __restrict__ num_t, const float* __restrict__ den_t,
                            float* __restrict__ out) {
    const int tid = threadIdx.x;
    float s = 0.0f;
    for (int t = tid; t < NT; t += 256) s += num_t[t] / (den_t[t] + 1e-5f);
#pragma unroll
    for (int off = 32; off > 0; off >>= 1) s += __shfl_down(s, off, 64);
    __shared__ float red[4];
    if ((tid & 63) == 0) red[tid >> 6] = s;
    __syncthreads();
    if (tid == 0) out[0] = (red[0] + red[1] + red[2] + red[3]) / (float)NT;
}

extern "C" void kernel_launch(void* const* d_in, const int* in_sizes, int n_in,
                              void* d_out, int out_size, void* d_ws, size_t ws_size,
                              hipStream_t stream) {
    const float* values  = (const float*)d_in[0];
    const float* masks   = (const float*)d_in[1];
    const float* evals   = (const float*)d_in[2];
    const float* emask   = (const float*)d_in[3];
    const float* istrain = (const float*)d_in[4];
    const float* W_ih    = (const float*)d_in[5];
    const float* W_hh    = (const float*)d_in[6];
    const float* b_ih    = (const float*)d_in[7];
    const float* b_hh    = (const float*)d_in[8];
    const float* W_reg   = (const float*)d_in[9];
    const float* b_reg   = (const float*)d_in[10];

    float* out = (float*)d_out;
    float* ws = (float*)d_ws;
    float* num_t = ws;
    float* den_t = ws + NT;
    float* amt = ws + WS_AMT_OFF;

    const bool pathA = ws_size >= (size_t)(WS_AMT_OFF + (long)NB * NT) * 4;

    if (pathA) {
        copy_zero_kernel<<<1024, 256, 0, stream>>>(evals, emask, istrain, out, ws, WS_AMT_OFF);
        lstm_kernel<0><<<NB, 64, 0, stream>>>(values, masks, W_ih, W_hh, b_ih, b_hh,
                                              W_reg, b_reg, out + OFF_IMP, amt);
        reduce_kernel<0><<<dim3(NT / 256, 64), 256, 0, stream>>>(masks, amt, num_t, den_t);
    } else {
        copy_zero_kernel<<<1024, 256, 0, stream>>>(evals, emask, istrain, out, ws,
                                                   WS_AMT_OFF + NREP * NT);
        lstm_kernel<1><<<NB, 64, 0, stream>>>(values, masks, W_ih, W_hh, b_ih, b_hh,
                                              W_reg, b_reg, out + OFF_IMP, amt);
        reduce_kernel<1><<<dim3(NT / 256, 64), 256, 0, stream>>>(masks, amt, num_t, den_t);
    }
    loss_kernel<<<1, 256, 0, stream>>>(num_t, den_t, out);
}